// Round 1
// baseline (3373.112 us; speedup 1.0000x reference)
//
#include <hip/hip_runtime.h>

#define BB 2
#define NN 8192
#define EE 256
#define KNH 32
#define NKEEP 4096

// ws layout:
// part    : [2][32][256] double @ 0        (131072 B)
// gm      : [2][256]     double @ 131072   (  4096 B)
// ld      : [2][8192]    double @ 135168   (131072 B)
// pos2idx : [2][4096]    int    @ 266240   ( 32768 B)

__global__ void k_gm_partial(const float* __restrict__ x, double* __restrict__ part) {
    const int b = blockIdx.y, chunk = blockIdx.x, t = threadIdx.x;
    const float* xp = x + ((size_t)b * NN + (size_t)chunk * 256) * EE + t;
    double s = 0.0;
    for (int i = 0; i < 256; ++i) s += (double)xp[(size_t)i * EE];
    part[((size_t)b * 32 + chunk) * EE + t] = s;
}

__global__ void k_gm_final(const double* __restrict__ part, double* __restrict__ gm) {
    const int b = blockIdx.y, t = threadIdx.x;
    double s = 0.0;
    for (int c = 0; c < 32; ++c) s += part[((size_t)b * 32 + c) * EE + t];
    gm[b * EE + t] = fabs(s / (double)NN);
}

// One wave per point: exact fp64 top-32 NN, fused with std + local_dist.
__global__ void k_knn_dist(const float* __restrict__ x, const float* __restrict__ coords,
                           const double* __restrict__ gm, double* __restrict__ ld_ws,
                           float* __restrict__ ld_out) {
    const int b    = blockIdx.y;
    const int wid  = threadIdx.x >> 6;
    const int lane = threadIdx.x & 63;
    const int i    = blockIdx.x * 4 + wid;

    const float* cs0 = coords + (size_t)b * 2 * NN;
    const float* cs1 = cs0 + NN;
    const double ci0 = (double)cs0[i];
    const double ci1 = (double)cs1[i];

    // per-lane sorted (ascending) top-32 of this lane's 128 candidates
    double bd[KNH];
    int    bi[KNH];
#pragma unroll
    for (int k = 0; k < KNH; ++k) { bd[k] = 1e300; bi[k] = 0x7fffffff; }

    for (int t = 0; t < NN / 64; ++t) {
        const int j = lane + t * 64;
        const double dx = ci0 - (double)cs0[j];
        const double dy = ci1 - (double)cs1[j];
        const double d  = dx * dx + dy * dy;
        // branchless stable sorted insert (equal dist -> keep earlier j)
#pragma unroll
        for (int k = KNH - 1; k >= 1; --k) {
            const bool up   = d < bd[k - 1];
            const bool here = (!up) && (d < bd[k]);
            bd[k] = up ? bd[k - 1] : (here ? d : bd[k]);
            bi[k] = up ? bi[k - 1] : (here ? j : bi[k]);
        }
        const bool h0 = d < bd[0];
        bd[0] = h0 ? d : bd[0];
        bi[0] = h0 ? j : bi[0];
    }

    // merge 64 sorted lists: 32 rounds of wave-argmin (index tie-break)
    int jkeep = 0x7fffffff;   // lane k ends holding the k-th nearest index (k<32)
    for (int k = 0; k < KNH; ++k) {
        double h  = bd[0];
        int    hj = bi[0];
#pragma unroll
        for (int s = 1; s < 64; s <<= 1) {
            const double od = __shfl_xor(h, s);
            const int    oj = __shfl_xor(hj, s);
            const bool take = (od < h) || (od == h && oj < hj);
            h  = take ? od : h;
            hj = take ? oj : hj;
        }
        if (lane == k) jkeep = hj;
        if (bi[0] == hj) {   // j's are unique across lanes; heads always real for k<32
#pragma unroll
            for (int m = 0; m < KNH - 1; ++m) { bd[m] = bd[m + 1]; bi[m] = bi[m + 1]; }
            bd[KNH - 1] = 1e300; bi[KNH - 1] = 0x7fffffff;
        }
    }

    // gather 32 neighbor rows, accumulate sum & sumsq per channel (4 ch/lane)
    double s1[4] = {0.0, 0.0, 0.0, 0.0};
    double s2[4] = {0.0, 0.0, 0.0, 0.0};
    const float* xb = x + (size_t)b * NN * EE;
    for (int k = 0; k < KNH; ++k) {
        const int j = __shfl(jkeep, k);
        const float4 v = *reinterpret_cast<const float4*>(xb + (size_t)j * EE + (lane << 2));
        const double v0 = (double)v.x, v1 = (double)v.y, v2 = (double)v.z, v3 = (double)v.w;
        s1[0] += v0; s2[0] += v0 * v0;
        s1[1] += v1; s2[1] += v1 * v1;
        s1[2] += v2; s2[2] += v2 * v2;
        s1[3] += v3; s2[3] += v3 * v3;
    }

    const double* gmb = gm + b * EE;
    double t = 0.0;
#pragma unroll
    for (int q = 0; q < 4; ++q) {
        const double sum = s1[q];
        double ssd = s2[q] - sum * sum * (1.0 / 32.0);
        ssd = ssd > 0.0 ? ssd : 0.0;
        const double ls = sqrt(ssd / 31.0);
        t += ls / gmb[(lane << 2) + q];
    }
#pragma unroll
    for (int s = 1; s < 64; s <<= 1) t += __shfl_xor(t, s);

    if (lane == 0) {
        ld_ws [(size_t)b * NN + i] = t;
        ld_out[(size_t)b * NN + i] = (float)t;
    }
}

// exact rank (= output position in desc top_k order with index tie-break)
__global__ void k_rank(const double* __restrict__ ld, int* __restrict__ pos2idx) {
    __shared__ double tile[2048];
    const int b = blockIdx.y;
    const int i = blockIdx.x * 256 + threadIdx.x;
    const double di = ld[(size_t)b * NN + i];
    int rank = 0;
    for (int t0 = 0; t0 < NN; t0 += 2048) {
        __syncthreads();
        for (int u = threadIdx.x; u < 2048; u += 256) tile[u] = ld[(size_t)b * NN + t0 + u];
        __syncthreads();
        for (int u = 0; u < 2048; ++u) {
            const double dj = tile[u];
            const int j = t0 + u;
            rank += (dj > di || (dj == di && j < i)) ? 1 : 0;
        }
    }
    if (rank < NKEEP) pos2idx[b * NKEEP + rank] = i;
}

__global__ void k_gather(const float* __restrict__ x, const float* __restrict__ coords,
                         const int* __restrict__ pos2idx,
                         float* __restrict__ x_out, float* __restrict__ c_out) {
    const int b    = blockIdx.y;
    const int wid  = threadIdx.x >> 6;
    const int lane = threadIdx.x & 63;
    const int r    = blockIdx.x * 4 + wid;
    const int i    = pos2idx[b * NKEEP + r];
    const float4 v = *reinterpret_cast<const float4*>(x + ((size_t)b * NN + i) * EE + (lane << 2));
    *reinterpret_cast<float4*>(x_out + ((size_t)b * NKEEP + r) * EE + (lane << 2)) = v;
    if (lane < 2) {
        c_out[((size_t)b * 2 + lane) * NKEEP + r] = coords[((size_t)b * 2 + lane) * NN + i];
    }
}

extern "C" void kernel_launch(void* const* d_in, const int* in_sizes, int n_in,
                              void* d_out, int out_size, void* d_ws, size_t ws_size,
                              hipStream_t stream) {
    const float* x      = (const float*)d_in[0];
    const float* coords = (const float*)d_in[1];

    float* out    = (float*)d_out;
    float* x_out  = out;                 // [2][4096][256]
    float* c_out  = out + 2097152;       // [2][2][4096][1]
    float* ld_out = out + 2113536;       // [2][8192]

    char*   ws      = (char*)d_ws;
    double* part    = (double*)(ws);
    double* gm      = (double*)(ws + 131072);
    double* ld      = (double*)(ws + 135168);
    int*    pos2idx = (int*)  (ws + 266240);

    k_gm_partial<<<dim3(32, 2),   256, 0, stream>>>(x, part);
    k_gm_final  <<<dim3(1, 2),    256, 0, stream>>>(part, gm);
    k_knn_dist  <<<dim3(2048, 2), 256, 0, stream>>>(x, coords, gm, ld, ld_out);
    k_rank      <<<dim3(32, 2),   256, 0, stream>>>(ld, pos2idx);
    k_gather    <<<dim3(1024, 2), 256, 0, stream>>>(x, coords, pos2idx, x_out, c_out);
}

// Round 2
// 298.851 us; speedup vs baseline: 11.2869x; 11.2869x over previous
//
#include <hip/hip_runtime.h>

#define NN 8192
#define EE 256
#define KNH 32
#define NKEEP 4096

typedef unsigned long long u64;
typedef unsigned int u32;

// ws layout:
// part    : [2][32][256] double @ 0        (131072 B)
// gm      : [2][256]     double @ 131072   (  4096 B)
// ld      : [2][8192]    double @ 135168   (131072 B)
// pos2idx : [2][4096]    int    @ 266240   ( 32768 B)

__global__ void k_gm_partial(const float* __restrict__ x, double* __restrict__ part) {
    const int b = blockIdx.y, chunk = blockIdx.x, t = threadIdx.x;
    const float* xp = x + ((size_t)b * NN + (size_t)chunk * 256) * EE + t;
    double s = 0.0;
    for (int i = 0; i < 256; ++i) s += (double)xp[(size_t)i * EE];
    part[((size_t)b * 32 + chunk) * EE + t] = s;
}

__global__ void k_gm_final(const double* __restrict__ part, double* __restrict__ gm) {
    const int b = blockIdx.y, t = threadIdx.x;
    double s = 0.0;
    for (int c = 0; c < 32; ++c) s += part[((size_t)b * 32 + c) * EE + t];
    gm[b * EE + t] = fabs(s / (double)NN);
}

__device__ __forceinline__ u64 wave_min_u64(u64 h) {
#pragma unroll
    for (int s = 1; s < 64; s <<= 1) {
        u32 hi = (u32)(h >> 32), lo = (u32)h;
        u32 ohi = __shfl_xor((int)hi, s);
        u32 olo = __shfl_xor((int)lo, s);
        u64 o = ((u64)ohi << 32) | olo;
        h = (o < h) ? o : h;
    }
    return h;
}

// One wave per point: top-32 NN via per-lane 8-deep register lists + wave merge,
// with exactness certificate + rare exact-restream fallback. Fused std+local_dist.
__global__ void k_knn_dist(const float* __restrict__ x, const float* __restrict__ coords,
                           const double* __restrict__ gm, double* __restrict__ ld_ws,
                           float* __restrict__ ld_out) {
    const int b    = blockIdx.y;
    const int wid  = threadIdx.x >> 6;
    const int lane = threadIdx.x & 63;
    const int i    = blockIdx.x * 4 + wid;

    const float* cs0 = coords + (size_t)b * 2 * NN;
    const float* cs1 = cs0 + NN;
    const float ci0 = cs0[i];
    const float ci1 = cs1[i];

    // per-lane sorted (ascending) top-8 keys; key = (f32_dist_bits << 32) | j
    u64 K0 = ~0ull, K1 = ~0ull, K2 = ~0ull, K3 = ~0ull;
    u64 K4 = ~0ull, K5 = ~0ull, K6 = ~0ull, K7 = ~0ull;

    for (int t = 0; t < NN / 64; ++t) {
        const int j = lane + t * 64;
        const float dx = ci0 - cs0[j];
        const float dy = ci1 - cs1[j];
        const float d  = fmaf(dx, dx, dy * dy);
        const u64 key = ((u64)__float_as_uint(d) << 32) | (u32)j;
        // branchless sorted insert, evaluated top-down on old values
        K7 = (key < K6) ? K6 : ((key < K7) ? key : K7);
        K6 = (key < K5) ? K5 : ((key < K6) ? key : K6);
        K5 = (key < K4) ? K4 : ((key < K5) ? key : K5);
        K4 = (key < K3) ? K3 : ((key < K4) ? key : K4);
        K3 = (key < K2) ? K2 : ((key < K3) ? key : K3);
        K2 = (key < K1) ? K1 : ((key < K2) ? key : K2);
        K1 = (key < K0) ? K0 : ((key < K1) ? key : K1);
        K0 = (key < K0) ? key : K0;
    }
    const u64 Kworst = K7;   // all dropped candidates have key >= Kworst

    // merge 64 sorted 8-lists: 32 rounds of wave-argmin with pop
    int jkeep = 0;           // lane k ends holding the k-th nearest index (k<32)
    u64 key32 = 0;           // key of the last (32nd) selected
    for (int k = 0; k < KNH; ++k) {
        const u64 h = wave_min_u64(K0);
        if (lane == k) jkeep = (int)(u32)h;
        key32 = h;
        const bool pop = (K0 == h);   // keys unique -> exactly one lane pops
        K0 = pop ? K1 : K0;
        K1 = pop ? K2 : K1;
        K2 = pop ? K3 : K2;
        K3 = pop ? K4 : K3;
        K4 = pop ? K5 : K4;
        K5 = pop ? K6 : K5;
        K6 = pop ? K7 : K6;
        K7 = pop ? ~0ull : K7;
    }

    // exactness certificate: no lane may have dropped a candidate below key32
    if (!__all(Kworst >= key32)) {
        // exact fallback: 32 rounds, each re-streams all candidates
        u64 minkeep = 0;
        for (int k = 0; k < KNH; ++k) {
            u64 best = ~0ull;
            for (int t = 0; t < NN / 64; ++t) {
                const int j = lane + t * 64;
                const float dx = ci0 - cs0[j];
                const float dy = ci1 - cs1[j];
                const float d  = fmaf(dx, dx, dy * dy);
                const u64 key = ((u64)__float_as_uint(d) << 32) | (u32)j;
                if (key >= minkeep && key < best) best = key;
            }
            const u64 h = wave_min_u64(best);
            if (lane == k) jkeep = (int)(u32)h;
            minkeep = h + 1;
        }
    }

    // gather 32 neighbor rows, accumulate sum & sumsq per channel (4 ch/lane)
    double s1[4] = {0.0, 0.0, 0.0, 0.0};
    double s2[4] = {0.0, 0.0, 0.0, 0.0};
    const float* xb = x + (size_t)b * NN * EE;
    for (int k = 0; k < KNH; ++k) {
        const int j = __shfl(jkeep, k);
        const float4 v = *reinterpret_cast<const float4*>(xb + (size_t)j * EE + (lane << 2));
        const double v0 = (double)v.x, v1 = (double)v.y, v2 = (double)v.z, v3 = (double)v.w;
        s1[0] += v0; s2[0] += v0 * v0;
        s1[1] += v1; s2[1] += v1 * v1;
        s1[2] += v2; s2[2] += v2 * v2;
        s1[3] += v3; s2[3] += v3 * v3;
    }

    const double* gmb = gm + b * EE;
    double t = 0.0;
#pragma unroll
    for (int q = 0; q < 4; ++q) {
        const double sum = s1[q];
        double ssd = s2[q] - sum * sum * (1.0 / 32.0);
        ssd = ssd > 0.0 ? ssd : 0.0;
        const double ls = sqrt(ssd / 31.0);
        t += ls / gmb[(lane << 2) + q];
    }
#pragma unroll
    for (int s = 1; s < 64; s <<= 1) t += __shfl_xor(t, s);

    if (lane == 0) {
        ld_ws [(size_t)b * NN + i] = t;
        ld_out[(size_t)b * NN + i] = (float)t;
    }
}

// exact rank (= output position in desc top_k order with index tie-break)
// one wave per point
__global__ void k_rank(const double* __restrict__ ld, int* __restrict__ pos2idx) {
    const int b    = blockIdx.y;
    const int wid  = threadIdx.x >> 6;
    const int lane = threadIdx.x & 63;
    const int i    = blockIdx.x * 4 + wid;
    const double* lb = ld + (size_t)b * NN;
    const double di = lb[i];
    int cnt = 0;
    for (int t = 0; t < NN / 64; ++t) {
        const int j = lane + t * 64;
        const double dj = lb[j];
        cnt += (dj > di || (dj == di && j < i)) ? 1 : 0;
    }
#pragma unroll
    for (int s = 1; s < 64; s <<= 1) cnt += __shfl_xor(cnt, s);
    if (lane == 0 && cnt < NKEEP) pos2idx[b * NKEEP + cnt] = i;
}

__global__ void k_gather(const float* __restrict__ x, const float* __restrict__ coords,
                         const int* __restrict__ pos2idx,
                         float* __restrict__ x_out, float* __restrict__ c_out) {
    const int b    = blockIdx.y;
    const int wid  = threadIdx.x >> 6;
    const int lane = threadIdx.x & 63;
    const int r    = blockIdx.x * 4 + wid;
    const int i    = pos2idx[b * NKEEP + r];
    const float4 v = *reinterpret_cast<const float4*>(x + ((size_t)b * NN + i) * EE + (lane << 2));
    *reinterpret_cast<float4*>(x_out + ((size_t)b * NKEEP + r) * EE + (lane << 2)) = v;
    if (lane < 2) {
        c_out[((size_t)b * 2 + lane) * NKEEP + r] = coords[((size_t)b * 2 + lane) * NN + i];
    }
}

extern "C" void kernel_launch(void* const* d_in, const int* in_sizes, int n_in,
                              void* d_out, int out_size, void* d_ws, size_t ws_size,
                              hipStream_t stream) {
    const float* x      = (const float*)d_in[0];
    const float* coords = (const float*)d_in[1];

    float* out    = (float*)d_out;
    float* x_out  = out;                 // [2][4096][256]
    float* c_out  = out + 2097152;       // [2][2][4096][1]
    float* ld_out = out + 2113536;       // [2][8192]

    char*   ws      = (char*)d_ws;
    double* part    = (double*)(ws);
    double* gm      = (double*)(ws + 131072);
    double* ld      = (double*)(ws + 135168);
    int*    pos2idx = (int*)  (ws + 266240);

    k_gm_partial<<<dim3(32, 2),   256, 0, stream>>>(x, part);
    k_gm_final  <<<dim3(1, 2),    256, 0, stream>>>(part, gm);
    k_knn_dist  <<<dim3(2048, 2), 256, 0, stream>>>(x, coords, gm, ld, ld_out);
    k_rank      <<<dim3(2048, 2), 256, 0, stream>>>(ld, pos2idx);
    k_gather    <<<dim3(1024, 2), 256, 0, stream>>>(x, coords, pos2idx, x_out, c_out);
}